// Round 14
// baseline (189.941 us; speedup 1.0000x reference)
//
#include <hip/hip_runtime.h>
#include <math.h>

namespace {

constexpr int Hh = 112, Ww = 112, Cc = 64, Nn = 16;
constexpr int OHh = 56, OWw = 56;
constexpr int HW = Hh * Ww;            // 12544
constexpr int OP = OHh * OWw;          // 3136
constexpr int NP = Nn * OP;            // 50176
constexpr int NHW = Nn * HW;           // 200704 = 196*1024
constexpr float BN_EPS_F = 1e-5f;
constexpr float CLAMP_MIN_F = 1e-4f;
constexpr int NSTAT = 32;
constexpr int CHS = 32;                // channels per part (NSPLIT=2)
constexpr int DEPTH = 6;               // prefetch depth (channels ahead)
constexpr int RING = 8;                // LDS ring buffers per wave

__device__ __forceinline__ void gload_lds16(const float* g, float* l) {
    __builtin_amdgcn_global_load_lds(
        (const __attribute__((address_space(1))) void*)g,
        (__attribute__((address_space(3))) void*)l, 16, 0, 0);
}

__device__ __forceinline__ void compute_from_lds(
    const float* __restrict__ buf, const float* __restrict__ wgt, int cg,
    int w0, int wm1, int wp2, float (&acc0)[9], float (&acc1)[9])
{
    float lft[3], rgt[3];
    float2 mid[3];
#pragma unroll
    for (int r = 0; r < 3; ++r) {
        mid[r] = *(const float2*)(buf + r * Ww + w0);   // 8B-aligned (w0 even)
        lft[r] = buf[r * Ww + wm1];
        rgt[r] = buf[r * Ww + wp2];
    }
#pragma unroll
    for (int k = 0; k < 9; ++k) {
        const float* wk = wgt + ((size_t)k * Cc + cg) * 9;   // uniform -> s_load
#pragma unroll
        for (int r = 0; r < 3; ++r) {
            const float wa = wk[3 * r], wb = wk[3 * r + 1], wc = wk[3 * r + 2];
            acc0[k] = fmaf(wa, lft[r],   acc0[k]);
            acc0[k] = fmaf(wb, mid[r].x, acc0[k]);
            acc0[k] = fmaf(wc, mid[r].y, acc0[k]);
            acc1[k] = fmaf(wa, mid[r].x, acc1[k]);
            acc1[k] = fmaf(wb, mid[r].y, acc1[k]);
            acc1[k] = fmaf(wc, rgt[r],   acc1[k]);
        }
    }
}

// K1: conv via wave-private LDS ring + global_load_lds (zero-VGPR prefetch).
// Block = 4 waves; wave owns one output row (2 px/lane, 56 active lanes).
// Per channel: 2 dwordx4 DMA instrs stage rows {h-1,h,h+1} (reflect folded
// into source addrs; halo cols are interior values under reflect). Counted
// s_waitcnt vmcnt(2*DEPTH) -> loads waited on were issued DEPTH iterations
// (~2000 cyc) earlier. NO barriers anywhere in the loop.
__global__ __launch_bounds__(256) void conv_lds_kernel(
    const float* __restrict__ x, const float* __restrict__ wgt,
    float* __restrict__ P /* [2][9][NHW] */)
{
    __shared__ __align__(16) float ring[4][RING][3 * Ww];   // 43008 B

    const int tid = threadIdx.x;
    const int lane = tid & 63;
    const int wv = tid >> 6;

    const int b = blockIdx.x;                  // 896 = 8 * 112
    const int swz = (b & 7) * 112 + (b >> 3);  // XCD k: contiguous swz chunk
    const int part = swz / 448;
    const int rem = swz - part * 448;
    const int n = rem / 28;
    const int h = (rem % 28) * 4 + wv;         // this wave's output row

    const int rs0 = (h == 0) ? 1 : h - 1;
    const int rs2 = (h == Hh - 1) ? (Hh - 2) : h + 1;

    // stage-slot source offsets: slot s -> row s/28, chunk s%28 (16B chunks)
    int so0, so1 = 0;
    {
        const int r = lane / 28, k = lane - r * 28;
        const int row = (r == 0) ? rs0 : ((r == 1) ? h : rs2);
        so0 = row * Ww + k * 4;
    }
    const bool act1 = (lane < 20);
    if (act1) {
        const int s1 = lane + 64;
        const int r = s1 / 28, k = s1 - r * 28;
        const int row = (r == 1) ? h : rs2;    // s1 in [64,84) -> r in {2} mostly, {1} for 64..83? r = s1/28: 64..83 -> 2
        so1 = ((s1 / 28 == 2) ? rs2 : ((s1 / 28 == 1) ? h : rs0)) * Ww + k * 4;
        (void)row;
    }

    const float* xb = x + ((size_t)n * Cc + part * CHS) * HW;

    // compute-side per-lane col indices (lanes >= 56 clamped; stores masked)
    const int l = (lane < 56) ? lane : 55;
    const int w0 = 2 * l;
    const int wm1 = (w0 == 0) ? 1 : w0 - 1;
    const int wp2 = (w0 + 1 == Ww - 1) ? (Ww - 2) : (w0 + 2);

    float acc0[9], acc1[9];
#pragma unroll
    for (int k = 0; k < 9; ++k) { acc0[k] = 0.f; acc1[k] = 0.f; }

#define STAGE(c)                                                                \
    {                                                                           \
        const float* src = xb + (size_t)(c) * HW;                               \
        float* dst = &ring[wv][(c) & (RING - 1)][0];                            \
        gload_lds16(src + so0, dst);                                            \
        if (act1) gload_lds16(src + so1, dst + 256);                            \
    }

    // prologue: channels 0..DEPTH-1 in flight
    STAGE(0) STAGE(1) STAGE(2) STAGE(3) STAGE(4) STAGE(5)

#define WAITN(c) (((c) + DEPTH < CHS) ? (2 * DEPTH) : (2 * (CHS - 1 - (c))))
#define STEP(c)                                                                 \
    {                                                                           \
        if constexpr ((c) + DEPTH < CHS) STAGE((c) + DEPTH)                     \
        asm volatile("s_waitcnt vmcnt(%0)" ::"i"(WAITN(c)) : "memory");         \
        __builtin_amdgcn_sched_barrier(0);                                      \
        compute_from_lds(&ring[wv][(c) & (RING - 1)][0], wgt,                   \
                         part * CHS + (c), w0, wm1, wp2, acc0, acc1);           \
    }

    STEP(0)  STEP(1)  STEP(2)  STEP(3)  STEP(4)  STEP(5)  STEP(6)  STEP(7)
    STEP(8)  STEP(9)  STEP(10) STEP(11) STEP(12) STEP(13) STEP(14) STEP(15)
    STEP(16) STEP(17) STEP(18) STEP(19) STEP(20) STEP(21) STEP(22) STEP(23)
    STEP(24) STEP(25) STEP(26) STEP(27) STEP(28) STEP(29) STEP(30) STEP(31)
#undef STEP
#undef WAITN
#undef STAGE

    if (lane < 56) {
        const int pos0 = n * HW + h * Ww + w0;
        float* Ph = P + (size_t)part * 9 * NHW;
#pragma unroll
        for (int k = 0; k < 9; ++k)
            *(float2*)(Ph + (size_t)k * NHW + pos0) = make_float2(acc0[k], acc1[k]);
    }
}

// K2: merge the 2 partials (float4/lane = 4 px), BN stats (spread atomics),
// extract even positions (aligned float2 stores).
__global__ __launch_bounds__(256) void merge_stats_kernel(
    const float* __restrict__ P, double* __restrict__ stats,
    float* __restrict__ sig_even /* [9][NP] */)
{
    __shared__ float rs[4], rq[4];
    const int tid = threadIdx.x;
    const int k = blockIdx.y;
    const int p0 = (blockIdx.x * 256 + tid) * 4;   // NHW = 196*1024

    float4 v = *(const float4*)(P + (size_t)k * NHW + p0);
    {
        const float4 t = *(const float4*)(P + ((size_t)9 + k) * NHW + p0);
        v.x += t.x; v.y += t.y; v.z += t.z; v.w += t.w;
    }

    const int w = p0 % Ww;                         // multiple of 4
    const int h = (p0 / Ww) % Hh;
    const int n = p0 / HW;
    if (!(h & 1)) {
        *(float2*)(sig_even + (size_t)k * NP + n * OP + (h >> 1) * OWw + (w >> 1)) =
            make_float2(v.x, v.z);
    }

    float s = v.x + v.y + v.z + v.w;
    float q = v.x * v.x + v.y * v.y + v.z * v.z + v.w * v.w;
#pragma unroll
    for (int off = 32; off > 0; off >>= 1) {
        s += __shfl_down(s, off, 64);
        q += __shfl_down(q, off, 64);
    }
    const int lane = tid & 63, wvv = tid >> 6;
    if (lane == 0) { rs[wvv] = s; rq[wvv] = q; }
    __syncthreads();
    if (tid == 0) {
        double* st = stats + (size_t)(blockIdx.x & (NSTAT - 1)) * 18;
        atomicAdd(&st[k], (double)(rs[0] + rs[1] + rs[2] + rs[3]));
        atomicAdd(&st[9 + k], (double)(rq[0] + rq[1] + rq[2] + rq[3]));
    }
}

// K3: fused normalize + apply. One block per (n, oh) row.
__global__ __launch_bounds__(256) void apply_kernel(
    const float* __restrict__ x, const float* __restrict__ sig_raw,
    const float* __restrict__ gamma, const float* __restrict__ beta,
    const double* __restrict__ stats, float* __restrict__ out)
{
    __shared__ float srow[9][OWw];
    __shared__ float mean_s[9], istd_s[9], gb[18];

    const int tid = threadIdx.x;
    const int f = blockIdx.x;                      // 896 = 8*112
    const int fs = (f & 7) * 112 + (f >> 3);
    const int n = fs / OHh;
    const int oh = fs % OHh;

    if (tid < 9) {
        double s = 0.0, q = 0.0;
        for (int r = 0; r < NSTAT; ++r) { s += stats[r * 18 + tid]; q += stats[r * 18 + 9 + tid]; }
        const double cnt = (double)Nn * HW;
        const double m = s / cnt;
        const double v = q / cnt - m * m;
        mean_s[tid] = (float)m;
        istd_s[tid] = (float)(1.0 / sqrt(v + (double)BN_EPS_F));
        gb[tid] = gamma[tid];
        gb[9 + tid] = beta[tid];
    }
    __syncthreads();

    if (tid < OWw) {
        const int pp = n * OP + oh * OWw + tid;
        float s[9], ssum = 0.f;
#pragma unroll
        for (int k = 0; k < 9; ++k) {
            float v = fmaf((sig_raw[(size_t)k * NP + pp] - mean_s[k]) * istd_s[k], gb[k], gb[9 + k]);
            v = fmaxf(v, CLAMP_MIN_F);
            s[k] = v;
            ssum += v;
        }
        const float inv = 1.f / ssum;
#pragma unroll
        for (int k = 0; k < 9; ++k) srow[k][tid] = s[k] * inv;
    }
    __syncthreads();

    const int csub = tid >> 6;
    const int lane = tid & 63;
    if (lane >= OWw) return;
    const int ow = lane;

    const int r0 = (oh == 0) ? 1 : (2 * oh - 1);
    const int r1 = 2 * oh, r2 = 2 * oh + 1;
    const int c0 = (ow == 0) ? 1 : (2 * ow - 1);
    const int c1 = 2 * ow, c2 = 2 * ow + 1;

    float sg[9];
#pragma unroll
    for (int k = 0; k < 9; ++k) sg[k] = srow[k][ow];

#pragma unroll 2
    for (int cc = 0; cc < 16; ++cc) {
        const int c = cc * 4 + csub;
        const float* xc = x + ((size_t)(n * Cc + c)) * HW;
        float o = 0.f;
        o = fmaf(sg[0], xc[r0 * Ww + c0], o);
        o = fmaf(sg[1], xc[r0 * Ww + c1], o);
        o = fmaf(sg[2], xc[r0 * Ww + c2], o);
        o = fmaf(sg[3], xc[r1 * Ww + c0], o);
        o = fmaf(sg[4], xc[r1 * Ww + c1], o);
        o = fmaf(sg[5], xc[r1 * Ww + c2], o);
        o = fmaf(sg[6], xc[r2 * Ww + c0], o);
        o = fmaf(sg[7], xc[r2 * Ww + c1], o);
        o = fmaf(sg[8], xc[r2 * Ww + c2], o);
        out[((size_t)(n * Cc + c)) * OP + oh * OWw + ow] = o;
    }
}

} // namespace

extern "C" void kernel_launch(void* const* d_in, const int* in_sizes, int n_in,
                              void* d_out, int out_size, void* d_ws, size_t ws_size,
                              hipStream_t stream) {
    const float* x     = (const float*)d_in[0];
    const float* wgt   = (const float*)d_in[1];
    const float* gamma = (const float*)d_in[2];
    const float* beta  = (const float*)d_in[3];
    float* out = (float*)d_out;

    double* stats = (double*)d_ws;                 // NSTAT*18 doubles
    float* P = (float*)((char*)d_ws + 8192);       // 2*9*NHW floats = 14.45 MB
    float* sig_even = P + (size_t)18 * NHW;        // 9*NP floats = 1.81 MB

    hipMemsetAsync(d_ws, 0, 8192, stream);
    conv_lds_kernel<<<896, 256, 0, stream>>>(x, wgt, P);
    merge_stats_kernel<<<dim3(196, 9), 256, 0, stream>>>(P, stats, sig_even);
    apply_kernel<<<896, 256, 0, stream>>>(x, sig_even, gamma, beta, stats, out);
}

// Round 15
// 99.358 us; speedup vs baseline: 1.9117x; 1.9117x over previous
//
#include <hip/hip_runtime.h>
#include <math.h>

namespace {

constexpr int Hh = 112, Ww = 112, Cc = 64, Nn = 16;
constexpr int OHh = 56, OWw = 56;
constexpr int HW = Hh * Ww;            // 12544
constexpr int OP = OHh * OWw;          // 3136
constexpr int NP = Nn * OP;            // 50176
constexpr int NHW = Nn * HW;           // 200704 = 196*1024
constexpr float BN_EPS_F = 1e-5f;
constexpr float CLAMP_MIN_F = 1e-4f;
constexpr int NSTAT = 32;
constexpr int CHS = 32;                // channels per part (2-way split)
constexpr int G = 4;                   // channels per pipeline phase
constexpr int NG = CHS / G;            // 8 phases

__device__ __forceinline__ int reflect_idx(int t) {
    t = t < 0 ? -t : t;
    return (t >= Hh) ? (2 * Hh - 2 - t) : t;
}

__device__ __forceinline__ void gload_lds16(const float* g, float* l) {
    __builtin_amdgcn_global_load_lds(
        (const __attribute__((address_space(1))) void*)g,
        (__attribute__((address_space(3))) void*)l, 16, 0, 0);
}

// K1: conv via block-cooperative row staging + group-granular double buffer.
// Block = 4 waves = output rows h0..h0+3; per channel stage 6 full 112-wide
// source rows (contiguous in global; reflect folded into row index).
// Phase = G=4 channels: one wave DMA-stages one channel (3 global_load_lds,
// zero VGPRs). compute(g) covers ~1300 cyc -> vmcnt(3) wait for group g+1
// (issued a full phase earlier) is free. Raw barriers only - no vmcnt(0)
// drain of in-flight prefetch. Plain loop -> low VGPR (R13/R14 lesson).
__global__ __launch_bounds__(256) void conv_rows_kernel(
    const float* __restrict__ x, const float* __restrict__ wgt,
    float* __restrict__ P /* [2][9][NHW] */)
{
    __shared__ __align__(16) float buf[2][G][6 * Ww];   // 21504 B

    const int tid = threadIdx.x;
    const int lane = tid & 63;
    const int wv = tid >> 6;

    const int b = blockIdx.x;                  // 896 = 8 * 112
    const int swz = (b & 7) * 112 + (b >> 3);  // XCD-contiguous chunks
    const int part = swz / 448;
    const int rem = swz - part * 448;
    const int n = rem / 28;
    const int h0 = (rem % 28) * 4;

    // stage source offsets (slot sl -> row sl/28, 16B chunk sl%28)
    int so_[3];
#pragma unroll
    for (int p = 0; p < 3; ++p) {
        int sl = p * 64 + lane;
        if (sl > 167) sl = 167;                // masked lanes: safe addr
        const int r = sl / 28, j = sl - r * 28;
        so_[p] = reflect_idx(h0 - 1 + r) * Ww + j * 4;
    }

    const float* xb = x + ((size_t)n * Cc + part * CHS) * HW;

    // compute-side column indices (lane owns cols 2l, 2l+1 of row h0+wv)
    const int l = (lane < 56) ? lane : 55;
    const int c0 = 2 * l;
    const int cm = (l == 0) ? 1 : c0 - 1;      // column reflect via LDS index
    const int cp = (l == 55) ? (Ww - 2) : c0 + 2;

    float acc0[9], acc1[9];
#pragma unroll
    for (int k = 0; k < 9; ++k) { acc0[k] = 0.f; acc1[k] = 0.f; }

#define STAGE(gg)                                                              \
    {                                                                          \
        const float* src = xb + (size_t)((gg) * G + wv) * HW;                  \
        float* dst = &buf[(gg) & 1][wv][0];                                    \
        gload_lds16(src + so_[0], dst);                                        \
        gload_lds16(src + so_[1], dst + 256);                                  \
        if (lane < 40) gload_lds16(src + so_[2], dst + 512);                   \
    }

    STAGE(0)
    STAGE(1)
    asm volatile("s_waitcnt vmcnt(3)" ::: "memory");
    __builtin_amdgcn_s_barrier();

    for (int g = 0; g < NG; ++g) {
        // compute group g from buf[g&1]
        const float* Bb = &buf[g & 1][0][0];
#pragma unroll
        for (int cg = 0; cg < G; ++cg) {
            const float* bc = Bb + cg * (6 * Ww) + wv * Ww;   // rows wv..wv+2
            float v0[3], v1[3], v2[3], v3[3];
#pragma unroll
            for (int r = 0; r < 3; ++r) {
                const float* br = bc + r * Ww;
                v0[r] = br[cm]; v1[r] = br[c0]; v2[r] = br[c0 + 1]; v3[r] = br[cp];
            }
            const int cglob = part * CHS + g * G + cg;
#pragma unroll
            for (int k = 0; k < 9; ++k) {
                const float* wk = wgt + ((size_t)k * Cc + cglob) * 9;  // s_load
#pragma unroll
                for (int r = 0; r < 3; ++r) {
                    const float wa = wk[3 * r], wb = wk[3 * r + 1], wc = wk[3 * r + 2];
                    acc0[k] = fmaf(wa, v0[r], acc0[k]);
                    acc0[k] = fmaf(wb, v1[r], acc0[k]);
                    acc0[k] = fmaf(wc, v2[r], acc0[k]);
                    acc1[k] = fmaf(wa, v1[r], acc1[k]);
                    acc1[k] = fmaf(wb, v2[r], acc1[k]);
                    acc1[k] = fmaf(wc, v3[r], acc1[k]);
                }
            }
        }

        // my LDS reads retired -> all waves done reading buf[g&1]
        asm volatile("s_waitcnt lgkmcnt(0)" ::: "memory");
        __builtin_amdgcn_s_barrier();

        if (g < NG - 2) {
            STAGE(g + 2)                               // refill freed buffer
            asm volatile("s_waitcnt vmcnt(3)" ::: "memory");   // group g+1 done
        } else {
            asm volatile("s_waitcnt vmcnt(0)" ::: "memory");
        }
        __builtin_amdgcn_s_barrier();                  // buf[(g+1)&1] ready
    }
#undef STAGE

    if (lane < 56) {
        const int pos0 = n * HW + (h0 + wv) * Ww + c0;
        float* Ph = P + (size_t)part * 9 * NHW;
#pragma unroll
        for (int k = 0; k < 9; ++k)
            *(float2*)(Ph + (size_t)k * NHW + pos0) = make_float2(acc0[k], acc1[k]);
    }
}

// K2: merge the 2 partials (float4/lane = 4 px), BN stats (spread atomics),
// extract even positions (aligned float2 stores).
__global__ __launch_bounds__(256) void merge_stats_kernel(
    const float* __restrict__ P, double* __restrict__ stats,
    float* __restrict__ sig_even /* [9][NP] */)
{
    __shared__ float rs[4], rq[4];
    const int tid = threadIdx.x;
    const int k = blockIdx.y;
    const int p0 = (blockIdx.x * 256 + tid) * 4;   // NHW = 196*1024

    float4 v = *(const float4*)(P + (size_t)k * NHW + p0);
    {
        const float4 t = *(const float4*)(P + ((size_t)9 + k) * NHW + p0);
        v.x += t.x; v.y += t.y; v.z += t.z; v.w += t.w;
    }

    const int w = p0 % Ww;                         // multiple of 4
    const int h = (p0 / Ww) % Hh;
    const int n = p0 / HW;
    if (!(h & 1)) {
        *(float2*)(sig_even + (size_t)k * NP + n * OP + (h >> 1) * OWw + (w >> 1)) =
            make_float2(v.x, v.z);
    }

    float s = v.x + v.y + v.z + v.w;
    float q = v.x * v.x + v.y * v.y + v.z * v.z + v.w * v.w;
#pragma unroll
    for (int off = 32; off > 0; off >>= 1) {
        s += __shfl_down(s, off, 64);
        q += __shfl_down(q, off, 64);
    }
    const int lane = tid & 63, wvv = tid >> 6;
    if (lane == 0) { rs[wvv] = s; rq[wvv] = q; }
    __syncthreads();
    if (tid == 0) {
        double* st = stats + (size_t)(blockIdx.x & (NSTAT - 1)) * 18;
        atomicAdd(&st[k], (double)(rs[0] + rs[1] + rs[2] + rs[3]));
        atomicAdd(&st[9 + k], (double)(rq[0] + rq[1] + rq[2] + rq[3]));
    }
}

// K3: fused normalize + apply. One block per (n, oh) row.
__global__ __launch_bounds__(256) void apply_kernel(
    const float* __restrict__ x, const float* __restrict__ sig_raw,
    const float* __restrict__ gamma, const float* __restrict__ beta,
    const double* __restrict__ stats, float* __restrict__ out)
{
    __shared__ float srow[9][OWw];
    __shared__ float mean_s[9], istd_s[9], gb[18];

    const int tid = threadIdx.x;
    const int f = blockIdx.x;                      // 896 = 8*112
    const int fs = (f & 7) * 112 + (f >> 3);
    const int n = fs / OHh;
    const int oh = fs % OHh;

    if (tid < 9) {
        double s = 0.0, q = 0.0;
        for (int r = 0; r < NSTAT; ++r) { s += stats[r * 18 + tid]; q += stats[r * 18 + 9 + tid]; }
        const double cnt = (double)Nn * HW;
        const double m = s / cnt;
        const double v = q / cnt - m * m;
        mean_s[tid] = (float)m;
        istd_s[tid] = (float)(1.0 / sqrt(v + (double)BN_EPS_F));
        gb[tid] = gamma[tid];
        gb[9 + tid] = beta[tid];
    }
    __syncthreads();

    if (tid < OWw) {
        const int pp = n * OP + oh * OWw + tid;
        float s[9], ssum = 0.f;
#pragma unroll
        for (int k = 0; k < 9; ++k) {
            float v = fmaf((sig_raw[(size_t)k * NP + pp] - mean_s[k]) * istd_s[k], gb[k], gb[9 + k]);
            v = fmaxf(v, CLAMP_MIN_F);
            s[k] = v;
            ssum += v;
        }
        const float inv = 1.f / ssum;
#pragma unroll
        for (int k = 0; k < 9; ++k) srow[k][tid] = s[k] * inv;
    }
    __syncthreads();

    const int csub = tid >> 6;
    const int lane = tid & 63;
    if (lane >= OWw) return;
    const int ow = lane;

    const int r0 = (oh == 0) ? 1 : (2 * oh - 1);
    const int r1 = 2 * oh, r2 = 2 * oh + 1;
    const int c0 = (ow == 0) ? 1 : (2 * ow - 1);
    const int c1 = 2 * ow, c2 = 2 * ow + 1;

    float sg[9];
#pragma unroll
    for (int k = 0; k < 9; ++k) sg[k] = srow[k][ow];

#pragma unroll 2
    for (int cc = 0; cc < 16; ++cc) {
        const int c = cc * 4 + csub;
        const float* xc = x + ((size_t)(n * Cc + c)) * HW;
        float o = 0.f;
        o = fmaf(sg[0], xc[r0 * Ww + c0], o);
        o = fmaf(sg[1], xc[r0 * Ww + c1], o);
        o = fmaf(sg[2], xc[r0 * Ww + c2], o);
        o = fmaf(sg[3], xc[r1 * Ww + c0], o);
        o = fmaf(sg[4], xc[r1 * Ww + c1], o);
        o = fmaf(sg[5], xc[r1 * Ww + c2], o);
        o = fmaf(sg[6], xc[r2 * Ww + c0], o);
        o = fmaf(sg[7], xc[r2 * Ww + c1], o);
        o = fmaf(sg[8], xc[r2 * Ww + c2], o);
        out[((size_t)(n * Cc + c)) * OP + oh * OWw + ow] = o;
    }
}

} // namespace

extern "C" void kernel_launch(void* const* d_in, const int* in_sizes, int n_in,
                              void* d_out, int out_size, void* d_ws, size_t ws_size,
                              hipStream_t stream) {
    const float* x     = (const float*)d_in[0];
    const float* wgt   = (const float*)d_in[1];
    const float* gamma = (const float*)d_in[2];
    const float* beta  = (const float*)d_in[3];
    float* out = (float*)d_out;

    double* stats = (double*)d_ws;                 // NSTAT*18 doubles
    float* P = (float*)((char*)d_ws + 8192);       // 2*9*NHW floats = 14.45 MB
    float* sig_even = P + (size_t)18 * NHW;        // 9*NP floats = 1.81 MB

    hipMemsetAsync(d_ws, 0, 8192, stream);
    conv_rows_kernel<<<896, 256, 0, stream>>>(x, wgt, P);
    merge_stats_kernel<<<dim3(196, 9), 256, 0, stream>>>(P, stats, sig_even);
    apply_kernel<<<896, 256, 0, stream>>>(x, sig_even, gamma, beta, stats, out);
}

// Round 16
// 71.650 us; speedup vs baseline: 2.6510x; 1.3867x over previous
//
#include <hip/hip_runtime.h>
#include <math.h>

namespace {

constexpr int Hh = 112, Ww = 112, Cc = 64, Nn = 16;
constexpr int OHh = 56, OWw = 56;
constexpr int HW = Hh * Ww;            // 12544 = 49*256
constexpr int OP = OHh * OWw;          // 3136
constexpr int NP = Nn * OP;            // 50176
constexpr int NHW = Nn * HW;           // 200704 = 196*1024
constexpr float BN_EPS_F = 1e-5f;
constexpr float CLAMP_MIN_F = 1e-4f;
constexpr int NSTAT = 32;

struct WSet { float m0[3], m1[3], el[3], er[3]; };   // 3x4 window, 1x2 strip

__device__ __forceinline__ void load_set(WSet& s, const float* __restrict__ base,
                                         const int (&ro)[3], int w0, int wl, int wr) {
#pragma unroll
    for (int r = 0; r < 3; ++r) {
        const float2 f2 = *(const float2*)(base + ro[r] + w0);
        s.m0[r] = f2.x; s.m1[r] = f2.y;
        s.el[r] = base[ro[r] + wl];
        s.er[r] = base[ro[r] + wr];
    }
}

__device__ __forceinline__ void compute_set(const WSet& s, const float* __restrict__ wgt,
                                            int cg, float (&acc0)[9], float (&acc1)[9]) {
#pragma unroll
    for (int k = 0; k < 9; ++k) {
        const float* wk = wgt + ((size_t)k * Cc + cg) * 9;   // uniform -> s_load
#pragma unroll
        for (int r = 0; r < 3; ++r) {
            const float wa = wk[3 * r], wb = wk[3 * r + 1], wc = wk[3 * r + 2];
            acc0[k] = fmaf(wa, s.el[r], acc0[k]);
            acc0[k] = fmaf(wb, s.m0[r], acc0[k]);
            acc0[k] = fmaf(wc, s.m1[r], acc0[k]);
            acc1[k] = fmaf(wa, s.m0[r], acc1[k]);
            acc1[k] = fmaf(wb, s.m1[r], acc1[k]);
            acc1[k] = fmaf(wc, s.er[r], acc1[k]);
        }
    }
}

// K1: R12's conv, VERBATIM (best measured: ~47-53 us, VGPR 44). Direct-load,
// 1x2 strip/lane, no LDS/barriers, compile-time channel unroll (scalar
// weight loads). FROZEN - 7 rounds of structural rewrites all regressed.
template <int NSPLIT>
__global__ __launch_bounds__(256) void conv_2deep_kernel(
    const float* __restrict__ x, const float* __restrict__ wgt,
    float* __restrict__ P /* [NSPLIT][9][NHW] */)
{
    constexpr int CHS = Cc / NSPLIT;
    constexpr int NBLK = NSPLIT * 392;

    const int tid = threadIdx.x;
    const int b = blockIdx.x;
    const int swz = (b & 7) * (NBLK / 8) + (b >> 3);   // XCD-contiguous chunks
    const int part = swz / 392;
    const int bid = swz - part * 392;

    const int s = bid * 256 + tid;                 // strip id; pixels 2s, 2s+1
    const int pos0 = 2 * s;
    const int n = pos0 / HW;
    const int hw = pos0 - n * HW;
    const int h = hw / Ww;
    const int w0 = hw - h * Ww;                    // even, 0..110

    const int hm = (h == 0) ? 1 : h - 1;
    const int hp = (h == Hh - 1) ? (Hh - 2) : (h + 1);
    const int wl = (w0 == 0) ? 1 : w0 - 1;
    const int wr = (w0 == Ww - 2) ? (Ww - 2) : (w0 + 2);

    const int ro[3] = { hm * Ww, h * Ww, hp * Ww };

    const float* xb = x + ((size_t)n * Cc + part * CHS) * HW;

    float acc0[9], acc1[9];
#pragma unroll
    for (int k = 0; k < 9; ++k) { acc0[k] = 0.f; acc1[k] = 0.f; }

    WSet A, B, C;
    load_set(A, xb, ro, w0, wl, wr);
    load_set(B, xb + HW, ro, w0, wl, wr);

#define STEP(c, SC, SF)                                                          \
    if constexpr ((c) < CHS) {                                                   \
        if constexpr ((c) + 2 < CHS)                                             \
            load_set(SF, xb + (size_t)((c) + 2) * HW, ro, w0, wl, wr);           \
        compute_set(SC, wgt, part * CHS + (c), acc0, acc1);                      \
    }

    STEP(0,  A, C) STEP(1,  B, A) STEP(2,  C, B)
    STEP(3,  A, C) STEP(4,  B, A) STEP(5,  C, B)
    STEP(6,  A, C) STEP(7,  B, A) STEP(8,  C, B)
    STEP(9,  A, C) STEP(10, B, A) STEP(11, C, B)
    STEP(12, A, C) STEP(13, B, A) STEP(14, C, B)
    STEP(15, A, C) STEP(16, B, A) STEP(17, C, B)
    STEP(18, A, C) STEP(19, B, A) STEP(20, C, B)
    STEP(21, A, C) STEP(22, B, A) STEP(23, C, B)
    STEP(24, A, C) STEP(25, B, A) STEP(26, C, B)
    STEP(27, A, C) STEP(28, B, A) STEP(29, C, B)
    STEP(30, A, C) STEP(31, B, A)
#undef STEP

    float* Ph = P + (size_t)part * 9 * NHW;
#pragma unroll
    for (int k = 0; k < 9; ++k)
        *(float2*)(Ph + (size_t)k * NHW + pos0) = make_float2(acc0[k], acc1[k]);
}

// K2: merge NSPLIT partials (float4/lane = 4 px), BN stats (spread atomics),
// extract even positions (aligned float2 stores). Unchanged.
template <int NSPLIT>
__global__ __launch_bounds__(256) void merge_stats_kernel(
    const float* __restrict__ P, double* __restrict__ stats,
    float* __restrict__ sig_even /* [9][NP] */)
{
    __shared__ float rs[4], rq[4];
    const int tid = threadIdx.x;
    const int k = blockIdx.y;
    const int p0 = (blockIdx.x * 256 + tid) * 4;   // NHW = 196*1024

    float4 v = *(const float4*)(P + (size_t)k * NHW + p0);
#pragma unroll
    for (int qq = 1; qq < NSPLIT; ++qq) {
        const float4 t = *(const float4*)(P + ((size_t)qq * 9 + k) * NHW + p0);
        v.x += t.x; v.y += t.y; v.z += t.z; v.w += t.w;
    }

    const int w = p0 % Ww;                         // multiple of 4
    const int h = (p0 / Ww) % Hh;
    const int n = p0 / HW;
    if (!(h & 1)) {
        *(float2*)(sig_even + (size_t)k * NP + n * OP + (h >> 1) * OWw + (w >> 1)) =
            make_float2(v.x, v.z);
    }

    float s = v.x + v.y + v.z + v.w;
    float q = v.x * v.x + v.y * v.y + v.z * v.z + v.w * v.w;
#pragma unroll
    for (int off = 32; off > 0; off >>= 1) {
        s += __shfl_down(s, off, 64);
        q += __shfl_down(q, off, 64);
    }
    const int lane = tid & 63, wv = tid >> 6;
    if (lane == 0) { rs[wv] = s; rq[wv] = q; }
    __syncthreads();
    if (tid == 0) {
        double* st = stats + (size_t)(blockIdx.x & (NSTAT - 1)) * 18;
        atomicAdd(&st[k], (double)(rs[0] + rs[1] + rs[2] + rs[3]));
        atomicAdd(&st[9 + k], (double)(rq[0] + rq[1] + rq[2] + rq[3]));
    }
}

// K3: fused normalize + apply, channel-split 4-ways across blocks to fix
// under-occupancy (was 896 blocks = 3.5/CU, 16 serial channel-iters of 9
// scattered loads each -> latency-exposed; now 3584 blocks = 14/CU, 4
// iters each). srow rebuilt per quarter (~1 us total, cheap).
__global__ __launch_bounds__(256) void apply_kernel(
    const float* __restrict__ x, const float* __restrict__ sig_raw,
    const float* __restrict__ gamma, const float* __restrict__ beta,
    const double* __restrict__ stats, float* __restrict__ out)
{
    __shared__ float srow[9][OWw];
    __shared__ float mean_s[9], istd_s[9], gb[18];

    const int tid = threadIdx.x;
    const int f = blockIdx.x;                      // 3584 = 8*448
    const int swz = (f & 7) * 448 + (f >> 3);
    const int q = swz / 896;                       // channel quarter
    const int fs = swz - q * 896;
    const int n = fs / OHh;
    const int oh = fs % OHh;

    if (tid < 9) {
        double s = 0.0, qq = 0.0;
        for (int r = 0; r < NSTAT; ++r) { s += stats[r * 18 + tid]; qq += stats[r * 18 + 9 + tid]; }
        const double cnt = (double)Nn * HW;
        const double m = s / cnt;
        const double v = qq / cnt - m * m;
        mean_s[tid] = (float)m;
        istd_s[tid] = (float)(1.0 / sqrt(v + (double)BN_EPS_F));
        gb[tid] = gamma[tid];
        gb[9 + tid] = beta[tid];
    }
    __syncthreads();

    if (tid < OWw) {
        const int pp = n * OP + oh * OWw + tid;
        float s[9], ssum = 0.f;
#pragma unroll
        for (int k = 0; k < 9; ++k) {
            float v = fmaf((sig_raw[(size_t)k * NP + pp] - mean_s[k]) * istd_s[k], gb[k], gb[9 + k]);
            v = fmaxf(v, CLAMP_MIN_F);
            s[k] = v;
            ssum += v;
        }
        const float inv = 1.f / ssum;
#pragma unroll
        for (int k = 0; k < 9; ++k) srow[k][tid] = s[k] * inv;
    }
    __syncthreads();

    const int csub = tid >> 6;                     // wave-uniform channel sub-index
    const int lane = tid & 63;
    if (lane >= OWw) return;                       // no barriers after this point
    const int ow = lane;

    const int r0 = (oh == 0) ? 1 : (2 * oh - 1);
    const int r1 = 2 * oh, r2 = 2 * oh + 1;
    const int c0 = (ow == 0) ? 1 : (2 * ow - 1);
    const int c1 = 2 * ow, c2 = 2 * ow + 1;

    float sg[9];
#pragma unroll
    for (int k = 0; k < 9; ++k) sg[k] = srow[k][ow];

#pragma unroll
    for (int cc = 0; cc < 4; ++cc) {
        const int c = q * 16 + cc * 4 + csub;
        const float* xc = x + ((size_t)(n * Cc + c)) * HW;
        float o = 0.f;
        o = fmaf(sg[0], xc[r0 * Ww + c0], o);
        o = fmaf(sg[1], xc[r0 * Ww + c1], o);
        o = fmaf(sg[2], xc[r0 * Ww + c2], o);
        o = fmaf(sg[3], xc[r1 * Ww + c0], o);
        o = fmaf(sg[4], xc[r1 * Ww + c1], o);
        o = fmaf(sg[5], xc[r1 * Ww + c2], o);
        o = fmaf(sg[6], xc[r2 * Ww + c0], o);
        o = fmaf(sg[7], xc[r2 * Ww + c1], o);
        o = fmaf(sg[8], xc[r2 * Ww + c2], o);
        out[((size_t)(n * Cc + c)) * OP + oh * OWw + ow] = o;
    }
}

} // namespace

extern "C" void kernel_launch(void* const* d_in, const int* in_sizes, int n_in,
                              void* d_out, int out_size, void* d_ws, size_t ws_size,
                              hipStream_t stream) {
    const float* x     = (const float*)d_in[0];
    const float* wgt   = (const float*)d_in[1];
    const float* gamma = (const float*)d_in[2];
    const float* beta  = (const float*)d_in[3];
    float* out = (float*)d_out;

    double* stats = (double*)d_ws;                 // NSTAT*18 doubles = 4608 B
    float* P = (float*)((char*)d_ws + 8192);

    const size_t sig_bytes = (size_t)9 * NP * 4;   // 1.81 MB
    const size_t need4 = 8192 + (size_t)36 * NHW * 4 + sig_bytes;   // ~30.7 MB
    hipMemsetAsync(d_ws, 0, 8192, stream);

    if (ws_size >= need4) {
        float* sig_even = P + (size_t)36 * NHW;
        conv_2deep_kernel<4><<<1568, 256, 0, stream>>>(x, wgt, P);
        merge_stats_kernel<4><<<dim3(196, 9), 256, 0, stream>>>(P, stats, sig_even);
        apply_kernel<<<3584, 256, 0, stream>>>(x, sig_even, gamma, beta, stats, out);
    } else {
        float* sig_even = P + (size_t)18 * NHW;
        conv_2deep_kernel<2><<<784, 256, 0, stream>>>(x, wgt, P);
        merge_stats_kernel<2><<<dim3(196, 9), 256, 0, stream>>>(P, stats, sig_even);
        apply_kernel<<<3584, 256, 0, stream>>>(x, sig_even, gamma, beta, stats, out);
    }
}